// Round 1
// baseline (715.644 us; speedup 1.0000x reference)
//
#include <hip/hip_runtime.h>
#include <hip/hip_bf16.h>
#include <cstdint>
#include <cstddef>

#define D 128           // feature dim (D_IN == D_OUT == 128)
#define KNB 10          // NUM_NEIGHBORS
#define SENT 0x7FFFFFFF // empty-slot sentinel (> any edge id)

// ---------------------------------------------------------------------------
// Kernel 1: init slots[N*10] to SENT (ws is re-poisoned 0xAA before every call)
// ---------------------------------------------------------------------------
__global__ __launch_bounds__(256) void k_init(int* __restrict__ slots, int n) {
  int i = blockIdx.x * 256 + threadIdx.x;
  if (i < n) slots[i] = SENT;
}

// ---------------------------------------------------------------------------
// Kernel 2: lock-free 10-smallest-edge-id selection per row via atomicMin
// cascade. "First 10 edges in original order" == 10 smallest edge ids.
// Invariant: a value only falls off the end after being displaced through all
// 10 slots by strictly smaller values -> final slots hold exactly the 10
// smallest ids for that row (order in slots irrelevant for a mean).
// ---------------------------------------------------------------------------
__global__ __launch_bounds__(256) void k_scatter(const int* __restrict__ ei,
                                                 int* __restrict__ slots, int E) {
  int e = blockIdx.x * 256 + threadIdx.x;
  if (e >= E) return;
  int r = ei[e];          // row
  int v = e;              // key = edge id (original order)
  int* sl = slots + (size_t)r * KNB;
#pragma unroll
  for (int s = 0; s < KNB; ++s) {
    int old = atomicMin(&sl[s], v);
    if (old == SENT) break;        // landed in an empty slot
    v = v > old ? v : old;         // carry the displaced (or our own) value
  }
}

// ---------------------------------------------------------------------------
// Kernel 3: neighbor mean. One wave per node. Lanes 0..9 read slots; selected
// cols broadcast via shfl; features gathered as coalesced float2 (512B/wave).
// Writes agg into d_out (reused as scratch; GEMM is in-place-safe).
// ---------------------------------------------------------------------------
__global__ __launch_bounds__(256) void k_agg(const float* __restrict__ x,
                                             const int* __restrict__ ei,
                                             const int* __restrict__ slots,
                                             float* __restrict__ agg,
                                             int N, int E) {
  int wave = threadIdx.x >> 6;
  int lane = threadIdx.x & 63;
  int n = blockIdx.x * 4 + wave;
  if (n >= N) return;

  int eid = SENT;
  if (lane < KNB) eid = slots[(size_t)n * KNB + lane];
  bool valid = (lane < KNB) && (eid != SENT);
  unsigned long long m = __ballot(valid);
  int nsel = __popcll(m);
  int c = valid ? ei[(size_t)E + eid] : 0;   // col of my selected edge

  float2 acc = make_float2(0.f, 0.f);
  if (nsel > 0) {
    unsigned long long mm = m;
    while (mm) {
      int j = (int)__builtin_ctzll(mm);
      mm &= mm - 1;
      int cj = __shfl(c, j);                 // wave-uniform broadcast
      float2 v = reinterpret_cast<const float2*>(x + (size_t)cj * D)[lane];
      acc.x += v.x; acc.y += v.y;
    }
    float sc = 1.f / (float)nsel;
    acc.x *= sc; acc.y *= sc;
  } else {
    acc = reinterpret_cast<const float2*>(x + (size_t)n * D)[lane]; // deg==0 fallback
  }
  reinterpret_cast<float2*>(agg + (size_t)n * D)[lane] = acc;
}

// ---------------------------------------------------------------------------
// Kernel 4: out[n][o] = b[o] + sum_k agg[n][k] * W[o][k]
// 128-node tile / block of 256 threads / 8x8 register blocking / KC=32 chunks.
// LDS is k-major with +4-float pad: 16B-aligned ds_read_b128, sA reads
// conflict-free (4 distinct 32B groups per wave), sW reads 4-way (acceptable:
// VALU-bound at 128 cyc/k vs ~62 LDS cyc/k per wave).
// In-place safe (agg may alias out): a block reads only its own 128 rows and
// all reads precede the epilogue stores.
// ---------------------------------------------------------------------------
#define BN 128
#define KC 32
#define LDP 132  // padded LDS row stride (floats); 132*4=528B, 16B multiple

__global__ __launch_bounds__(256) void k_gemm(const float* __restrict__ agg,
                                              const float* __restrict__ Wm,
                                              const float* __restrict__ bias,
                                              float* __restrict__ out, int N) {
  __shared__ float sA[KC][LDP];
  __shared__ float sW[KC][LDP];
  const int tid = threadIdx.x;
  const int tx = tid & 15;   // out-dim group: outs tx*8 .. tx*8+7
  const int ty = tid >> 4;   // node group:  nodes ty*8 .. ty*8+7
  const int n0 = blockIdx.x * BN;

  float acc[8][8];
#pragma unroll
  for (int i = 0; i < 8; ++i)
#pragma unroll
    for (int j = 0; j < 8; ++j) acc[i][j] = 0.f;

  const int nl = tid >> 3;   // 0..31 (row within tile for staging)
  const int kq = tid & 7;    // 0..7  (float4 index within k-chunk)

  for (int kc = 0; kc < D; kc += KC) {
#pragma unroll
    for (int i = 0; i < 4; ++i) {
      int rrow = nl + i * 32;          // 0..127
      int n = n0 + rrow;
      float4 av = make_float4(0.f, 0.f, 0.f, 0.f);
      if (n < N)
        av = reinterpret_cast<const float4*>(agg + (size_t)n * D + kc)[kq];
      int k = kq * 4;
      sA[k+0][rrow] = av.x; sA[k+1][rrow] = av.y;
      sA[k+2][rrow] = av.z; sA[k+3][rrow] = av.w;
      float4 wv = reinterpret_cast<const float4*>(Wm + (size_t)rrow * D + kc)[kq];
      sW[k+0][rrow] = wv.x; sW[k+1][rrow] = wv.y;
      sW[k+2][rrow] = wv.z; sW[k+3][rrow] = wv.w;
    }
    __syncthreads();
#pragma unroll
    for (int k = 0; k < KC; ++k) {
      float4 a0 = *reinterpret_cast<const float4*>(&sA[k][ty * 8]);
      float4 a1 = *reinterpret_cast<const float4*>(&sA[k][ty * 8 + 4]);
      float4 w0 = *reinterpret_cast<const float4*>(&sW[k][tx * 8]);
      float4 w1 = *reinterpret_cast<const float4*>(&sW[k][tx * 8 + 4]);
      float a[8] = {a0.x, a0.y, a0.z, a0.w, a1.x, a1.y, a1.z, a1.w};
      float w[8] = {w0.x, w0.y, w0.z, w0.w, w1.x, w1.y, w1.z, w1.w};
#pragma unroll
      for (int i = 0; i < 8; ++i)
#pragma unroll
        for (int j = 0; j < 8; ++j)
          acc[i][j] += a[i] * w[j];
    }
    __syncthreads();
  }

  float4 b0 = reinterpret_cast<const float4*>(bias)[tx * 2];
  float4 b1 = reinterpret_cast<const float4*>(bias)[tx * 2 + 1];
#pragma unroll
  for (int i = 0; i < 8; ++i) {
    int n = n0 + ty * 8 + i;
    if (n < N) {
      float4 v0 = make_float4(acc[i][0] + b0.x, acc[i][1] + b0.y,
                              acc[i][2] + b0.z, acc[i][3] + b0.w);
      float4 v1 = make_float4(acc[i][4] + b1.x, acc[i][5] + b1.y,
                              acc[i][6] + b1.z, acc[i][7] + b1.w);
      float4* op = reinterpret_cast<float4*>(out + (size_t)n * D + tx * 8);
      op[0] = v0;
      op[1] = v1;
    }
  }
}

// ---------------------------------------------------------------------------
extern "C" void kernel_launch(void* const* d_in, const int* in_sizes, int n_in,
                              void* d_out, int out_size, void* d_ws, size_t ws_size,
                              hipStream_t stream) {
  const float* x    = (const float*)d_in[0];  // [N,128] fp32
  const int*   ei   = (const int*)d_in[1];    // [2,E] int (row=ei[0:E], col=ei[E:2E])
  const float* Wm   = (const float*)d_in[2];  // [128,128] fp32 (row-major, [o][k])
  const float* bias = (const float*)d_in[3];  // [128] fp32
  float* out = (float*)d_out;                 // [N,128] fp32

  const int N = in_sizes[0] / D;
  const int E = in_sizes[1] / 2;

  int* slots = (int*)d_ws;                    // N*10 ints = 4 MB
  const int S = N * KNB;

  k_init<<<(S + 255) / 256, 256, 0, stream>>>(slots, S);
  k_scatter<<<(E + 255) / 256, 256, 0, stream>>>(ei, slots, E);
  // agg written into d_out; k_gemm then reads/writes d_out in place (safe:
  // each block reads only its own rows, all reads before epilogue stores).
  k_agg<<<(N + 3) / 4, 256, 0, stream>>>(x, ei, slots, out, N, E);
  k_gemm<<<(N + BN - 1) / BN, 256, 0, stream>>>(out, Wm, bias, out, N);
}

// Round 2
// 295.344 us; speedup vs baseline: 2.4231x; 2.4231x over previous
//
#include <hip/hip_runtime.h>
#include <hip/hip_bf16.h>
#include <cstdint>
#include <cstddef>

#define D 128           // feature dim (D_IN == D_OUT == 128)
#define KNB 10          // NUM_NEIGHBORS
#define SENT 0x7FFFFFFF // empty-slot sentinel (> any packed edge id)
#define SHIFT 8         // nodes per bucket = 256
#define NPB 256         // 1 << SHIFT
#define T_BIN 256
#define EPB 4096        // edges per binning block
#define MAXNB 1024      // max buckets supported (N <= 262144)

// ---------------------------------------------------------------------------
// k_zero: zero the bucket-count array (ws is poisoned 0xAA each call)
// ---------------------------------------------------------------------------
__global__ __launch_bounds__(256) void k_zero(int* __restrict__ p, int n) {
  int i = blockIdx.x * 256 + threadIdx.x;
  if (i < n) p[i] = 0;
}

// ---------------------------------------------------------------------------
// k_count: per-block LDS histogram of edge rows into NB node-range buckets,
// then one global atomicAdd per (block,bucket). ~150K global atomics total
// (vs 5.6M device-scope atomics in the old k_scatter).
// ---------------------------------------------------------------------------
__global__ __launch_bounds__(T_BIN) void k_count(const int* __restrict__ row, int E,
                                                 int NB, int* __restrict__ counts) {
  __shared__ int hist[MAXNB];
  for (int i = threadIdx.x; i < NB; i += T_BIN) hist[i] = 0;
  __syncthreads();
  int e0 = blockIdx.x * EPB;
  for (int i = threadIdx.x; i < EPB; i += T_BIN) {
    int e = e0 + i;
    if (e < E) atomicAdd(&hist[row[e] >> SHIFT], 1);
  }
  __syncthreads();
  for (int i = threadIdx.x; i < NB; i += T_BIN)
    if (hist[i]) atomicAdd(&counts[i], hist[i]);
}

// ---------------------------------------------------------------------------
// k_scan: single-block exclusive scan of NB bucket counts -> bases & cursors.
// ---------------------------------------------------------------------------
__global__ __launch_bounds__(MAXNB) void k_scan(const int* __restrict__ counts, int NB,
                                                int* __restrict__ bases,
                                                int* __restrict__ cursor) {
  __shared__ int buf[MAXNB];
  int t = threadIdx.x;
  int v = (t < NB) ? counts[t] : 0;
  buf[t] = v;
  __syncthreads();
  for (int off = 1; off < MAXNB; off <<= 1) {
    int xv = (t >= off) ? buf[t - off] : 0;
    __syncthreads();
    buf[t] += xv;
    __syncthreads();
  }
  if (t < NB) {
    int base = buf[t] - v;   // exclusive
    bases[t] = base;
    cursor[t] = base;
  }
}

// ---------------------------------------------------------------------------
// k_scatter2: bin edges. Per-block LDS histogram -> one global atomicAdd per
// (block,bucket) reserves a contiguous range; LDS cursors place each edge.
// Entry packs (row & 255) << 24 | edge_id  (E < 2^24). Within-bucket order is
// irrelevant: the selection key is the edge id itself.
// ---------------------------------------------------------------------------
__global__ __launch_bounds__(T_BIN) void k_scatter2(const int* __restrict__ row, int E,
                                                    int NB, int* __restrict__ cursor,
                                                    unsigned* __restrict__ binned) {
  __shared__ int hist[MAXNB];
  __shared__ int lbase[MAXNB];
  for (int i = threadIdx.x; i < NB; i += T_BIN) hist[i] = 0;
  __syncthreads();
  int e0 = blockIdx.x * EPB;
  for (int i = threadIdx.x; i < EPB; i += T_BIN) {
    int e = e0 + i;
    if (e < E) atomicAdd(&hist[row[e] >> SHIFT], 1);
  }
  __syncthreads();
  for (int i = threadIdx.x; i < NB; i += T_BIN) {
    int h = hist[i];
    lbase[i] = h ? atomicAdd(&cursor[i], h) : 0;
  }
  __syncthreads();
  for (int i = threadIdx.x; i < NB; i += T_BIN) hist[i] = 0;  // reuse as local cursor
  __syncthreads();
  for (int i = threadIdx.x; i < EPB; i += T_BIN) {
    int e = e0 + i;
    if (e < E) {
      int r = row[e];
      int b = r >> SHIFT;
      int pos = lbase[b] + atomicAdd(&hist[b], 1);
      binned[pos] = ((unsigned)(r & (NPB - 1)) << 24) | (unsigned)e;
    }
  }
}

// ---------------------------------------------------------------------------
// k_select: one WG per bucket. LDS atomicMin cascade (the proven 10-smallest
// invariant, now on LDS where atomics are cheap), then coalesced slot dump.
// ---------------------------------------------------------------------------
__global__ __launch_bounds__(256) void k_select(const unsigned* __restrict__ binned,
                                                const int* __restrict__ bases,
                                                const int* __restrict__ counts,
                                                int* __restrict__ slots_g, int N) {
  __shared__ int sl[NPB * KNB];
  int b = blockIdx.x;
  int nbase = b << SHIFT;
  int nloc = min(NPB, N - nbase);
  for (int i = threadIdx.x; i < nloc * KNB; i += 256) sl[i] = SENT;
  __syncthreads();
  int base = bases[b], cnt = counts[b];
  for (int i = threadIdx.x; i < cnt; i += 256) {
    unsigned en = binned[base + i];
    int rl = (int)(en >> 24);
    int v = (int)(en & 0xFFFFFFu) & 0xFFFFFF;
    int* s = &sl[rl * KNB];
#pragma unroll
    for (int k = 0; k < KNB; ++k) {
      int old = atomicMin(&s[k], v);
      if (old == SENT) break;
      v = v > old ? v : old;
    }
  }
  __syncthreads();
  for (int i = threadIdx.x; i < nloc * KNB; i += 256)
    slots_g[(size_t)nbase * KNB + i] = sl[i];
}

// ---------------------------------------------------------------------------
// k_agg: neighbor mean. One wave per node. Lanes 0..9 read slots; selected
// cols broadcast via shfl; features gathered as coalesced float2 (512B/wave).
// Writes agg into d_out (reused as scratch; GEMM is in-place-safe).
// ---------------------------------------------------------------------------
__global__ __launch_bounds__(256) void k_agg(const float* __restrict__ x,
                                             const int* __restrict__ ei,
                                             const int* __restrict__ slots,
                                             float* __restrict__ agg,
                                             int N, int E) {
  int wave = threadIdx.x >> 6;
  int lane = threadIdx.x & 63;
  int n = blockIdx.x * 4 + wave;
  if (n >= N) return;

  int eid = SENT;
  if (lane < KNB) eid = slots[(size_t)n * KNB + lane];
  bool valid = (lane < KNB) && (eid != SENT);
  unsigned long long m = __ballot(valid);
  int nsel = __popcll(m);
  int c = valid ? ei[(size_t)E + eid] : 0;   // col of my selected edge

  float2 acc = make_float2(0.f, 0.f);
  if (nsel > 0) {
    unsigned long long mm = m;
    while (mm) {
      int j = (int)__builtin_ctzll(mm);
      mm &= mm - 1;
      int cj = __shfl(c, j);                 // wave-uniform broadcast
      float2 v = reinterpret_cast<const float2*>(x + (size_t)cj * D)[lane];
      acc.x += v.x; acc.y += v.y;
    }
    float sc = 1.f / (float)nsel;
    acc.x *= sc; acc.y *= sc;
  } else {
    acc = reinterpret_cast<const float2*>(x + (size_t)n * D)[lane]; // deg==0 fallback
  }
  reinterpret_cast<float2*>(agg + (size_t)n * D)[lane] = acc;
}

// ---------------------------------------------------------------------------
// k_gemm: out[n][o] = b[o] + sum_k agg[n][k] * W[o][k]
// 128-node tile / 256 threads / 8x8 register blocking / KC=32 chunks.
// In-place safe (agg may alias out): a block reads only its own 128 rows and
// all reads precede the epilogue stores.
// ---------------------------------------------------------------------------
#define BN 128
#define KC 32
#define LDP 132  // padded LDS row stride (floats)

__global__ __launch_bounds__(256) void k_gemm(const float* __restrict__ agg,
                                              const float* __restrict__ Wm,
                                              const float* __restrict__ bias,
                                              float* __restrict__ out, int N) {
  __shared__ float sA[KC][LDP];
  __shared__ float sW[KC][LDP];
  const int tid = threadIdx.x;
  const int tx = tid & 15;
  const int ty = tid >> 4;
  const int n0 = blockIdx.x * BN;

  float acc[8][8];
#pragma unroll
  for (int i = 0; i < 8; ++i)
#pragma unroll
    for (int j = 0; j < 8; ++j) acc[i][j] = 0.f;

  const int nl = tid >> 3;
  const int kq = tid & 7;

  for (int kc = 0; kc < D; kc += KC) {
#pragma unroll
    for (int i = 0; i < 4; ++i) {
      int rrow = nl + i * 32;
      int n = n0 + rrow;
      float4 av = make_float4(0.f, 0.f, 0.f, 0.f);
      if (n < N)
        av = reinterpret_cast<const float4*>(agg + (size_t)n * D + kc)[kq];
      int k = kq * 4;
      sA[k+0][rrow] = av.x; sA[k+1][rrow] = av.y;
      sA[k+2][rrow] = av.z; sA[k+3][rrow] = av.w;
      float4 wv = reinterpret_cast<const float4*>(Wm + (size_t)rrow * D + kc)[kq];
      sW[k+0][rrow] = wv.x; sW[k+1][rrow] = wv.y;
      sW[k+2][rrow] = wv.z; sW[k+3][rrow] = wv.w;
    }
    __syncthreads();
#pragma unroll
    for (int k = 0; k < KC; ++k) {
      float4 a0 = *reinterpret_cast<const float4*>(&sA[k][ty * 8]);
      float4 a1 = *reinterpret_cast<const float4*>(&sA[k][ty * 8 + 4]);
      float4 w0 = *reinterpret_cast<const float4*>(&sW[k][tx * 8]);
      float4 w1 = *reinterpret_cast<const float4*>(&sW[k][tx * 8 + 4]);
      float a[8] = {a0.x, a0.y, a0.z, a0.w, a1.x, a1.y, a1.z, a1.w};
      float w[8] = {w0.x, w0.y, w0.z, w0.w, w1.x, w1.y, w1.z, w1.w};
#pragma unroll
      for (int i = 0; i < 8; ++i)
#pragma unroll
        for (int j = 0; j < 8; ++j)
          acc[i][j] += a[i] * w[j];
    }
    __syncthreads();
  }

  float4 b0 = reinterpret_cast<const float4*>(bias)[tx * 2];
  float4 b1 = reinterpret_cast<const float4*>(bias)[tx * 2 + 1];
#pragma unroll
  for (int i = 0; i < 8; ++i) {
    int n = n0 + ty * 8 + i;
    if (n < N) {
      float4 v0 = make_float4(acc[i][0] + b0.x, acc[i][1] + b0.y,
                              acc[i][2] + b0.z, acc[i][3] + b0.w);
      float4 v1 = make_float4(acc[i][4] + b1.x, acc[i][5] + b1.y,
                              acc[i][6] + b1.z, acc[i][7] + b1.w);
      float4* op = reinterpret_cast<float4*>(out + (size_t)n * D + tx * 8);
      op[0] = v0;
      op[1] = v1;
    }
  }
}

// ---------------------------------------------------------------------------
extern "C" void kernel_launch(void* const* d_in, const int* in_sizes, int n_in,
                              void* d_out, int out_size, void* d_ws, size_t ws_size,
                              hipStream_t stream) {
  const float* x    = (const float*)d_in[0];  // [N,128] fp32
  const int*   ei   = (const int*)d_in[1];    // [2,E] int (row=ei[0:E], col=ei[E:2E])
  const float* Wm   = (const float*)d_in[2];  // [128,128] fp32
  const float* bias = (const float*)d_in[3];  // [128] fp32
  float* out = (float*)d_out;                 // [N,128] fp32

  const int N = in_sizes[0] / D;
  const int E = in_sizes[1] / 2;
  const int NB = (N + NPB - 1) >> SHIFT;      // 391 buckets

  // workspace layout (ints): slots[N*10] | counts[NB] | bases[NB] | cursor[NB]
  int* slots  = (int*)d_ws;
  int* counts = slots + (size_t)N * KNB;
  int* bases  = counts + NB;
  int* cursor = bases + NB;

  // binned edges staged in d_out's first E*4 bytes (consumed by k_select
  // before k_agg overwrites d_out with agg).
  unsigned* binned = (unsigned*)d_out;

  const int blocks_bin = (E + EPB - 1) / EPB;

  k_zero<<<(NB + 255) / 256, 256, 0, stream>>>(counts, NB);
  k_count<<<blocks_bin, T_BIN, 0, stream>>>(ei, E, NB, counts);
  k_scan<<<1, MAXNB, 0, stream>>>(counts, NB, bases, cursor);
  k_scatter2<<<blocks_bin, T_BIN, 0, stream>>>(ei, E, NB, cursor, binned);
  k_select<<<NB, 256, 0, stream>>>(binned, bases, counts, slots, N);
  k_agg<<<(N + 3) / 4, 256, 0, stream>>>(x, ei, slots, out, N, E);
  k_gemm<<<(N + BN - 1) / BN, 256, 0, stream>>>(out, Wm, bias, out, N);
}

// Round 4
// 295.282 us; speedup vs baseline: 2.4236x; 1.0002x over previous
//
#include <hip/hip_runtime.h>
#include <hip/hip_bf16.h>
#include <cstdint>
#include <cstddef>

#define D 128           // feature dim
#define KNB 10          // NUM_NEIGHBORS
#define SENT 0x7FFFFFFF
#define SHIFT 8         // nodes per bucket = 256
#define NPB 256
#define T_BIN 256
#define EPB 4096        // edges per binning block
#define MAXNB 1024

__device__ inline unsigned bf16_rne(float f) {
  unsigned u = __builtin_bit_cast(unsigned, f);
  return (u + 0x7FFFu + ((u >> 16) & 1u)) >> 16;
}

// ---------------------------------------------------------------------------
__global__ __launch_bounds__(256) void k_zero(int* __restrict__ p, int n) {
  int i = blockIdx.x * 256 + threadIdx.x;
  if (i < n) p[i] = 0;
}

__global__ __launch_bounds__(256) void k_fill(int* __restrict__ p, int n, int v) {
  int i = blockIdx.x * 256 + threadIdx.x;
  if (i < n) p[i] = v;
}

// ---------------------------------------------------------------------------
// per-block LDS histogram -> one global atomicAdd per (block,bucket)
// ---------------------------------------------------------------------------
__global__ __launch_bounds__(T_BIN) void k_count(const int* __restrict__ row, int E,
                                                 int NB, int* __restrict__ counts) {
  __shared__ int hist[MAXNB];
  for (int i = threadIdx.x; i < NB; i += T_BIN) hist[i] = 0;
  __syncthreads();
  int e0 = blockIdx.x * EPB;
  for (int i = threadIdx.x; i < EPB; i += T_BIN) {
    int e = e0 + i;
    if (e < E) atomicAdd(&hist[row[e] >> SHIFT], 1);
  }
  __syncthreads();
  for (int i = threadIdx.x; i < NB; i += T_BIN)
    if (hist[i]) atomicAdd(&counts[i], hist[i]);
}

// ---------------------------------------------------------------------------
__global__ __launch_bounds__(MAXNB) void k_scan(const int* __restrict__ counts, int NB,
                                                int* __restrict__ bases,
                                                int* __restrict__ cursor) {
  __shared__ int buf[MAXNB];
  int t = threadIdx.x;
  int v = (t < NB) ? counts[t] : 0;
  buf[t] = v;
  __syncthreads();
  for (int off = 1; off < MAXNB; off <<= 1) {
    int xv = (t >= off) ? buf[t - off] : 0;
    __syncthreads();
    buf[t] += xv;
    __syncthreads();
  }
  if (t < NB) {
    int base = buf[t] - v;
    bases[t] = base;
    cursor[t] = base;
  }
}

// ---------------------------------------------------------------------------
// bin edges into bucket regions; entry = (row&255)<<24 | edge_id (E < 2^24)
// ---------------------------------------------------------------------------
__global__ __launch_bounds__(T_BIN) void k_scatter2(const int* __restrict__ row, int E,
                                                    int NB, int* __restrict__ cursor,
                                                    unsigned* __restrict__ binned) {
  __shared__ int hist[MAXNB];
  __shared__ int lbase[MAXNB];
  for (int i = threadIdx.x; i < NB; i += T_BIN) hist[i] = 0;
  __syncthreads();
  int e0 = blockIdx.x * EPB;
  for (int i = threadIdx.x; i < EPB; i += T_BIN) {
    int e = e0 + i;
    if (e < E) atomicAdd(&hist[row[e] >> SHIFT], 1);
  }
  __syncthreads();
  for (int i = threadIdx.x; i < NB; i += T_BIN) {
    int h = hist[i];
    lbase[i] = h ? atomicAdd(&cursor[i], h) : 0;
  }
  __syncthreads();
  for (int i = threadIdx.x; i < NB; i += T_BIN) hist[i] = 0;  // reuse as cursor
  __syncthreads();
  for (int i = threadIdx.x; i < EPB; i += T_BIN) {
    int e = e0 + i;
    if (e < E) {
      int r = row[e];
      int b = r >> SHIFT;
      int pos = lbase[b] + atomicAdd(&hist[b], 1);
      binned[pos] = ((unsigned)(r & (NPB - 1)) << 24) | (unsigned)e;
    }
  }
}

// ---------------------------------------------------------------------------
// one WG per bucket: LDS atomicMin cascade -> 10 smallest edge ids per node
// ---------------------------------------------------------------------------
__global__ __launch_bounds__(256) void k_select(const unsigned* __restrict__ binned,
                                                const int* __restrict__ bases,
                                                const int* __restrict__ counts,
                                                int* __restrict__ slots_g, int N, int E) {
  __shared__ int sl[NPB * KNB];
  int b = blockIdx.x;
  int nbase = b << SHIFT;
  int nloc = min(NPB, N - nbase);
  for (int i = threadIdx.x; i < nloc * KNB; i += 256) sl[i] = SENT;
  __syncthreads();
  int base = bases[b];
  int cnt = counts[b];
  if (cnt > E) cnt = E;  // hardening: never trust a corrupt count
  for (int i = threadIdx.x; i < cnt; i += 256) {
    unsigned en = binned[base + i];
    int rl = (int)(en >> 24);
    int v = (int)(en & 0xFFFFFFu);
    int* s = &sl[rl * KNB];
#pragma unroll
    for (int k = 0; k < KNB; ++k) {
      int old = atomicMin(&s[k], v);
      if (old == SENT) break;
      v = v > old ? v : old;
    }
  }
  __syncthreads();
  for (int i = threadIdx.x; i < nloc * KNB; i += 256)
    slots_g[(size_t)nbase * KNB + i] = sl[i];
}

// ---------------------------------------------------------------------------
// x (fp32) -> xh (bf16 packed pairs). 8 floats/thread.
// ---------------------------------------------------------------------------
__global__ __launch_bounds__(256) void k_xcast(const float* __restrict__ x,
                                               unsigned* __restrict__ xh, int n8) {
  int t = blockIdx.x * 256 + threadIdx.x;
  if (t >= n8) return;
  const float4* p = reinterpret_cast<const float4*>(x) + (size_t)t * 2;
  float4 a = p[0], b = p[1];
  uint4 o;
  o.x = bf16_rne(a.x) | (bf16_rne(a.y) << 16);
  o.y = bf16_rne(a.z) | (bf16_rne(a.w) << 16);
  o.z = bf16_rne(b.x) | (bf16_rne(b.y) << 16);
  o.w = bf16_rne(b.z) | (bf16_rne(b.w) << 16);
  reinterpret_cast<uint4*>(xh)[t] = o;
}

// ---------------------------------------------------------------------------
// k_agg_h: neighbor mean gathering bf16 rows (256B/row), fp32 accumulate.
// One wave per node. HARDENED: any slot value outside [0,E) is invalid
// (covers SENT and 0xAA poison -> no OOB ei/xh reads ever); shuffled col is
// range-checked before indexing xh.
// ---------------------------------------------------------------------------
__global__ __launch_bounds__(256) void k_agg_h(const unsigned* __restrict__ xh,
                                               const float* __restrict__ x,
                                               const int* __restrict__ ei,
                                               const int* __restrict__ slots,
                                               float* __restrict__ agg, int N, int E) {
  int wave = threadIdx.x >> 6;
  int lane = threadIdx.x & 63;
  int n = blockIdx.x * 4 + wave;
  if (n >= N) return;

  int eid = SENT;
  if (lane < KNB) eid = slots[(size_t)n * KNB + lane];
  bool valid = (lane < KNB) && ((unsigned)eid < (unsigned)E);
  unsigned long long m = __ballot(valid);
  int nsel = __popcll(m);
  int c = valid ? ei[(size_t)E + eid] : 0;

  float ax = 0.f, ay = 0.f;
  if (nsel > 0) {
    unsigned long long mm = m;
    while (mm) {
      int j = (int)__builtin_ctzll(mm);
      mm &= mm - 1;
      int cj = __shfl(c, j);
      if ((unsigned)cj >= (unsigned)N) cj = 0;  // hardening
      unsigned u = xh[(size_t)cj * 64 + lane];  // 2 bf16 (elems 2*lane, 2*lane+1)
      ax += __builtin_bit_cast(float, u << 16);
      ay += __builtin_bit_cast(float, u & 0xFFFF0000u);
    }
    float sc = 1.f / (float)nsel;
    ax *= sc; ay *= sc;
  } else {
    float2 v = reinterpret_cast<const float2*>(x + (size_t)n * D)[lane];
    ax = v.x; ay = v.y;
  }
  reinterpret_cast<float2*>(agg + (size_t)n * D)[lane] = make_float2(ax, ay);
}

// ---------------------------------------------------------------------------
// fallback fp32 gather (used only if ws too small for xh)
// ---------------------------------------------------------------------------
__global__ __launch_bounds__(256) void k_agg(const float* __restrict__ x,
                                             const int* __restrict__ ei,
                                             const int* __restrict__ slots,
                                             float* __restrict__ agg,
                                             int N, int E) {
  int wave = threadIdx.x >> 6;
  int lane = threadIdx.x & 63;
  int n = blockIdx.x * 4 + wave;
  if (n >= N) return;
  int eid = SENT;
  if (lane < KNB) eid = slots[(size_t)n * KNB + lane];
  bool valid = (lane < KNB) && ((unsigned)eid < (unsigned)E);
  unsigned long long m = __ballot(valid);
  int nsel = __popcll(m);
  int c = valid ? ei[(size_t)E + eid] : 0;
  float2 acc = make_float2(0.f, 0.f);
  if (nsel > 0) {
    unsigned long long mm = m;
    while (mm) {
      int j = (int)__builtin_ctzll(mm);
      mm &= mm - 1;
      int cj = __shfl(c, j);
      if ((unsigned)cj >= (unsigned)N) cj = 0;
      float2 v = reinterpret_cast<const float2*>(x + (size_t)cj * D)[lane];
      acc.x += v.x; acc.y += v.y;
    }
    float sc = 1.f / (float)nsel;
    acc.x *= sc; acc.y *= sc;
  } else {
    acc = reinterpret_cast<const float2*>(x + (size_t)n * D)[lane];
  }
  reinterpret_cast<float2*>(agg + (size_t)n * D)[lane] = acc;
}

// ---------------------------------------------------------------------------
// k_gemm (R2-proven fp32 VALU GEMM): out[n][o] = b[o] + sum_k agg[n][k]*W[o][k]
// 128-node tile / 256 threads / 8x8 register blocking / KC=32 chunks.
// In-place safe (agg aliases out): block reads only its own 128 rows; all
// reads precede epilogue stores.
// ---------------------------------------------------------------------------
#define BN 128
#define KC 32
#define LDP 132

__global__ __launch_bounds__(256) void k_gemm(const float* __restrict__ agg,
                                              const float* __restrict__ Wm,
                                              const float* __restrict__ bias,
                                              float* __restrict__ out, int N) {
  __shared__ float sA[KC][LDP];
  __shared__ float sW[KC][LDP];
  const int tid = threadIdx.x;
  const int tx = tid & 15;
  const int ty = tid >> 4;
  const int n0 = blockIdx.x * BN;

  float acc[8][8];
#pragma unroll
  for (int i = 0; i < 8; ++i)
#pragma unroll
    for (int j = 0; j < 8; ++j) acc[i][j] = 0.f;

  const int nl = tid >> 3;
  const int kq = tid & 7;

  for (int kc = 0; kc < D; kc += KC) {
#pragma unroll
    for (int i = 0; i < 4; ++i) {
      int rrow = nl + i * 32;
      int n = n0 + rrow;
      float4 av = make_float4(0.f, 0.f, 0.f, 0.f);
      if (n < N)
        av = reinterpret_cast<const float4*>(agg + (size_t)n * D + kc)[kq];
      int k = kq * 4;
      sA[k+0][rrow] = av.x; sA[k+1][rrow] = av.y;
      sA[k+2][rrow] = av.z; sA[k+3][rrow] = av.w;
      float4 wv = reinterpret_cast<const float4*>(Wm + (size_t)rrow * D + kc)[kq];
      sW[k+0][rrow] = wv.x; sW[k+1][rrow] = wv.y;
      sW[k+2][rrow] = wv.z; sW[k+3][rrow] = wv.w;
    }
    __syncthreads();
#pragma unroll
    for (int k = 0; k < KC; ++k) {
      float4 a0 = *reinterpret_cast<const float4*>(&sA[k][ty * 8]);
      float4 a1 = *reinterpret_cast<const float4*>(&sA[k][ty * 8 + 4]);
      float4 w0 = *reinterpret_cast<const float4*>(&sW[k][tx * 8]);
      float4 w1 = *reinterpret_cast<const float4*>(&sW[k][tx * 8 + 4]);
      float a[8] = {a0.x, a0.y, a0.z, a0.w, a1.x, a1.y, a1.z, a1.w};
      float w[8] = {w0.x, w0.y, w0.z, w0.w, w1.x, w1.y, w1.z, w1.w};
#pragma unroll
      for (int i = 0; i < 8; ++i)
#pragma unroll
        for (int j = 0; j < 8; ++j)
          acc[i][j] += a[i] * w[j];
    }
    __syncthreads();
  }

  float4 b0 = reinterpret_cast<const float4*>(bias)[tx * 2];
  float4 b1 = reinterpret_cast<const float4*>(bias)[tx * 2 + 1];
#pragma unroll
  for (int i = 0; i < 8; ++i) {
    int n = n0 + ty * 8 + i;
    if (n < N) {
      float4 v0 = make_float4(acc[i][0] + b0.x, acc[i][1] + b0.y,
                              acc[i][2] + b0.z, acc[i][3] + b0.w);
      float4 v1 = make_float4(acc[i][4] + b1.x, acc[i][5] + b1.y,
                              acc[i][6] + b1.z, acc[i][7] + b1.w);
      float4* op = reinterpret_cast<float4*>(out + (size_t)n * D + tx * 8);
      op[0] = v0;
      op[1] = v1;
    }
  }
}

// ---------------------------------------------------------------------------
extern "C" void kernel_launch(void* const* d_in, const int* in_sizes, int n_in,
                              void* d_out, int out_size, void* d_ws, size_t ws_size,
                              hipStream_t stream) {
  const float* x    = (const float*)d_in[0];
  const int*   ei   = (const int*)d_in[1];
  const float* Wm   = (const float*)d_in[2];
  const float* bias = (const float*)d_in[3];
  float* out = (float*)d_out;

  const int N = in_sizes[0] / D;
  const int E = in_sizes[1] / 2;
  const int NB = (N + NPB - 1) >> SHIFT;

  // ws layout: counts|bases|cursor | slots[N*10] | xh (bf16 x, optional)
  int* counts = (int*)d_ws;
  int* bases  = counts + NB;
  int* cursor = bases + NB;
  size_t off_slots = ((size_t)(3 * NB) * 4 + 15) & ~(size_t)15;
  int* slots = (int*)((char*)d_ws + off_slots);
  size_t off_xh = (off_slots + (size_t)N * KNB * 4 + 15) & ~(size_t)15;
  unsigned* xh = (unsigned*)((char*)d_ws + off_xh);
  const bool fast = ws_size >= off_xh + (size_t)N * D * 2;

  unsigned* binned = (unsigned*)d_out;  // staged in d_out, dead after k_select
  const int blocks_bin = (E + EPB - 1) / EPB;
  const int S = N * KNB;

  k_zero<<<(NB + 255) / 256, 256, 0, stream>>>(counts, NB);
  k_fill<<<(S + 255) / 256, 256, 0, stream>>>(slots, S, SENT);  // insurance
  k_count<<<blocks_bin, T_BIN, 0, stream>>>(ei, E, NB, counts);
  k_scan<<<1, MAXNB, 0, stream>>>(counts, NB, bases, cursor);
  k_scatter2<<<blocks_bin, T_BIN, 0, stream>>>(ei, E, NB, cursor, binned);
  k_select<<<NB, 256, 0, stream>>>(binned, bases, counts, slots, N, E);
  if (fast) {
    k_xcast<<<(N * (D / 8) + 255) / 256, 256, 0, stream>>>(x, xh, N * (D / 8));
    k_agg_h<<<(N + 3) / 4, 256, 0, stream>>>(xh, x, ei, slots, out, N, E);
  } else {
    k_agg<<<(N + 3) / 4, 256, 0, stream>>>(x, ei, slots, out, N, E);
  }
  k_gemm<<<(N + BN - 1) / BN, 256, 0, stream>>>(out, Wm, bias, out, N);
}

// Round 5
// 249.694 us; speedup vs baseline: 2.8661x; 1.1826x over previous
//
#include <hip/hip_runtime.h>
#include <hip/hip_bf16.h>
#include <cstdint>
#include <cstddef>

#define D 128           // feature dim
#define KNB 10          // NUM_NEIGHBORS
#define SENT 0x7FFFFFFF
#define SHIFT 8         // nodes per bucket = 256
#define NPB 256
#define T_BIN 256
#define EPB 4096        // edges per binning block
#define MAXNB 1024

typedef __attribute__((ext_vector_type(8))) short short8;   // MFMA A/B frag (8 bf16)
typedef __attribute__((ext_vector_type(4))) float floatx4;  // MFMA C/D frag

__device__ inline unsigned bf16_rne(float f) {
  unsigned u = __builtin_bit_cast(unsigned, f);
  return (u + 0x7FFFu + ((u >> 16) & 1u)) >> 16;
}

// ---------------------------------------------------------------------------
// k_init2: counts[0..NB)=0 and slots[0..S)=SENT in one launch (grid covers S)
// ---------------------------------------------------------------------------
__global__ __launch_bounds__(256) void k_init2(int* __restrict__ counts, int NB,
                                               int* __restrict__ slots, int S) {
  int i = blockIdx.x * 256 + threadIdx.x;
  if (i < NB) counts[i] = 0;
  if (i < S) slots[i] = SENT;
}

// ---------------------------------------------------------------------------
// k_count_xcast: blocks [0,blocks_bin) do the LDS-histogram edge count;
// blocks [blocks_bin,..) stream-cast x fp32 -> xh bf16 pairs (overlapped).
// ---------------------------------------------------------------------------
__global__ __launch_bounds__(T_BIN) void k_count_xcast(const int* __restrict__ row, int E,
                                                       int NB, int* __restrict__ counts,
                                                       int blocks_bin,
                                                       const float* __restrict__ x,
                                                       unsigned* __restrict__ xh, int n8) {
  if ((int)blockIdx.x < blocks_bin) {
    __shared__ int hist[MAXNB];
    for (int i = threadIdx.x; i < NB; i += T_BIN) hist[i] = 0;
    __syncthreads();
    int e0 = blockIdx.x * EPB;
    for (int i = threadIdx.x; i < EPB; i += T_BIN) {
      int e = e0 + i;
      if (e < E) atomicAdd(&hist[row[e] >> SHIFT], 1);
    }
    __syncthreads();
    for (int i = threadIdx.x; i < NB; i += T_BIN)
      if (hist[i]) atomicAdd(&counts[i], hist[i]);
  } else {
    int t = ((int)blockIdx.x - blocks_bin) * T_BIN + threadIdx.x;
    if (t >= n8) return;
    const float4* p = reinterpret_cast<const float4*>(x) + (size_t)t * 2;
    float4 a = p[0], b = p[1];
    uint4 o;
    o.x = bf16_rne(a.x) | (bf16_rne(a.y) << 16);
    o.y = bf16_rne(a.z) | (bf16_rne(a.w) << 16);
    o.z = bf16_rne(b.x) | (bf16_rne(b.y) << 16);
    o.w = bf16_rne(b.z) | (bf16_rne(b.w) << 16);
    reinterpret_cast<uint4*>(xh)[t] = o;
  }
}

// ---------------------------------------------------------------------------
__global__ __launch_bounds__(MAXNB) void k_scan(const int* __restrict__ counts, int NB,
                                                int* __restrict__ bases,
                                                int* __restrict__ cursor) {
  __shared__ int buf[MAXNB];
  int t = threadIdx.x;
  int v = (t < NB) ? counts[t] : 0;
  buf[t] = v;
  __syncthreads();
  for (int off = 1; off < MAXNB; off <<= 1) {
    int xv = (t >= off) ? buf[t - off] : 0;
    __syncthreads();
    buf[t] += xv;
    __syncthreads();
  }
  if (t < NB) {
    int base = buf[t] - v;
    bases[t] = base;
    cursor[t] = base;
  }
}

// ---------------------------------------------------------------------------
// bin edges into bucket regions; entry = (row&255)<<24 | edge_id (E < 2^24)
// ---------------------------------------------------------------------------
__global__ __launch_bounds__(T_BIN) void k_scatter2(const int* __restrict__ row, int E,
                                                    int NB, int* __restrict__ cursor,
                                                    unsigned* __restrict__ binned) {
  __shared__ int hist[MAXNB];
  __shared__ int lbase[MAXNB];
  for (int i = threadIdx.x; i < NB; i += T_BIN) hist[i] = 0;
  __syncthreads();
  int e0 = blockIdx.x * EPB;
  for (int i = threadIdx.x; i < EPB; i += T_BIN) {
    int e = e0 + i;
    if (e < E) atomicAdd(&hist[row[e] >> SHIFT], 1);
  }
  __syncthreads();
  for (int i = threadIdx.x; i < NB; i += T_BIN) {
    int h = hist[i];
    lbase[i] = h ? atomicAdd(&cursor[i], h) : 0;
  }
  __syncthreads();
  for (int i = threadIdx.x; i < NB; i += T_BIN) hist[i] = 0;  // reuse as cursor
  __syncthreads();
  for (int i = threadIdx.x; i < EPB; i += T_BIN) {
    int e = e0 + i;
    if (e < E) {
      int r = row[e];
      int b = r >> SHIFT;
      int pos = lbase[b] + atomicAdd(&hist[b], 1);
      binned[pos] = ((unsigned)(r & (NPB - 1)) << 24) | (unsigned)e;
    }
  }
}

// ---------------------------------------------------------------------------
// one WG per bucket: LDS atomicMin cascade -> 10 smallest edge ids per node
// ---------------------------------------------------------------------------
__global__ __launch_bounds__(256) void k_select(const unsigned* __restrict__ binned,
                                                const int* __restrict__ bases,
                                                const int* __restrict__ counts,
                                                int* __restrict__ slots_g, int N, int E) {
  __shared__ int sl[NPB * KNB];
  int b = blockIdx.x;
  int nbase = b << SHIFT;
  int nloc = min(NPB, N - nbase);
  for (int i = threadIdx.x; i < nloc * KNB; i += 256) sl[i] = SENT;
  __syncthreads();
  int base = bases[b];
  int cnt = counts[b];
  if (cnt > E) cnt = E;  // hardening
  for (int i = threadIdx.x; i < cnt; i += 256) {
    unsigned en = binned[base + i];
    int rl = (int)(en >> 24);
    int v = (int)(en & 0xFFFFFFu);
    int* s = &sl[rl * KNB];
#pragma unroll
    for (int k = 0; k < KNB; ++k) {
      int old = atomicMin(&s[k], v);
      if (old == SENT) break;
      v = v > old ? v : old;
    }
  }
  __syncthreads();
  for (int i = threadIdx.x; i < nloc * KNB; i += 256)
    slots_g[(size_t)nbase * KNB + i] = sl[i];
}

// ---------------------------------------------------------------------------
// k_agg_hb: neighbor mean via bf16 gather, fp32 accumulate, bf16 packed out.
// HARDENED validity: (unsigned)eid < E rejects SENT and any stray/poison-
// derived value (semantically exact: phantoms never displace real ids and
// are excluded from nsel).
// ---------------------------------------------------------------------------
__global__ __launch_bounds__(256) void k_agg_hb(const unsigned* __restrict__ xh,
                                                const float* __restrict__ x,
                                                const int* __restrict__ ei,
                                                const int* __restrict__ slots,
                                                unsigned* __restrict__ aggbh,
                                                int N, int E) {
  int wave = threadIdx.x >> 6;
  int lane = threadIdx.x & 63;
  int n = blockIdx.x * 4 + wave;
  if (n >= N) return;

  int eid = SENT;
  if (lane < KNB) eid = slots[(size_t)n * KNB + lane];
  bool valid = (lane < KNB) && ((unsigned)eid < (unsigned)E);
  unsigned long long m = __ballot(valid);
  int nsel = __popcll(m);
  int c = valid ? ei[(size_t)E + eid] : 0;

  float ax = 0.f, ay = 0.f;
  if (nsel > 0) {
    unsigned long long mm = m;
    while (mm) {
      int j = (int)__builtin_ctzll(mm);
      mm &= mm - 1;
      int cj = __shfl(c, j);
      if ((unsigned)cj >= (unsigned)N) cj = 0;  // hardening
      unsigned u = xh[(size_t)cj * 64 + lane];  // 2 bf16: elems 2*lane, 2*lane+1
      ax += __builtin_bit_cast(float, u << 16);
      ay += __builtin_bit_cast(float, u & 0xFFFF0000u);
    }
    float sc = 1.f / (float)nsel;
    ax *= sc; ay *= sc;
  } else {
    float2 v = reinterpret_cast<const float2*>(x + (size_t)n * D)[lane];
    ax = v.x; ay = v.y;
  }
  aggbh[(size_t)n * 64 + lane] = bf16_rne(ax) | (bf16_rne(ay) << 16);
}

// ---------------------------------------------------------------------------
// fallback fp32-agg variants (R4-proven), used when ws is small
// ---------------------------------------------------------------------------
__global__ __launch_bounds__(256) void k_agg_h(const unsigned* __restrict__ xh,
                                               const float* __restrict__ x,
                                               const int* __restrict__ ei,
                                               const int* __restrict__ slots,
                                               float* __restrict__ agg, int N, int E) {
  int wave = threadIdx.x >> 6;
  int lane = threadIdx.x & 63;
  int n = blockIdx.x * 4 + wave;
  if (n >= N) return;
  int eid = SENT;
  if (lane < KNB) eid = slots[(size_t)n * KNB + lane];
  bool valid = (lane < KNB) && ((unsigned)eid < (unsigned)E);
  unsigned long long m = __ballot(valid);
  int nsel = __popcll(m);
  int c = valid ? ei[(size_t)E + eid] : 0;
  float ax = 0.f, ay = 0.f;
  if (nsel > 0) {
    unsigned long long mm = m;
    while (mm) {
      int j = (int)__builtin_ctzll(mm);
      mm &= mm - 1;
      int cj = __shfl(c, j);
      if ((unsigned)cj >= (unsigned)N) cj = 0;
      unsigned u = xh[(size_t)cj * 64 + lane];
      ax += __builtin_bit_cast(float, u << 16);
      ay += __builtin_bit_cast(float, u & 0xFFFF0000u);
    }
    float sc = 1.f / (float)nsel;
    ax *= sc; ay *= sc;
  } else {
    float2 v = reinterpret_cast<const float2*>(x + (size_t)n * D)[lane];
    ax = v.x; ay = v.y;
  }
  reinterpret_cast<float2*>(agg + (size_t)n * D)[lane] = make_float2(ax, ay);
}

__global__ __launch_bounds__(256) void k_agg(const float* __restrict__ x,
                                             const int* __restrict__ ei,
                                             const int* __restrict__ slots,
                                             float* __restrict__ agg,
                                             int N, int E) {
  int wave = threadIdx.x >> 6;
  int lane = threadIdx.x & 63;
  int n = blockIdx.x * 4 + wave;
  if (n >= N) return;
  int eid = SENT;
  if (lane < KNB) eid = slots[(size_t)n * KNB + lane];
  bool valid = (lane < KNB) && ((unsigned)eid < (unsigned)E);
  unsigned long long m = __ballot(valid);
  int nsel = __popcll(m);
  int c = valid ? ei[(size_t)E + eid] : 0;
  float2 acc = make_float2(0.f, 0.f);
  if (nsel > 0) {
    unsigned long long mm = m;
    while (mm) {
      int j = (int)__builtin_ctzll(mm);
      mm &= mm - 1;
      int cj = __shfl(c, j);
      if ((unsigned)cj >= (unsigned)N) cj = 0;
      float2 v = reinterpret_cast<const float2*>(x + (size_t)cj * D)[lane];
      acc.x += v.x; acc.y += v.y;
    }
    float sc = 1.f / (float)nsel;
    acc.x *= sc; acc.y *= sc;
  } else {
    acc = reinterpret_cast<const float2*>(x + (size_t)n * D)[lane];
  }
  reinterpret_cast<float2*>(agg + (size_t)n * D)[lane] = acc;
}

// ---------------------------------------------------------------------------
// k_gemm_bf: out[n][o] = b[o] + sum_k aggbh[n][k]*W[o][k], bf16 MFMA 16x16x32.
// A read from ws (bf16), out only written -> no aliasing at all.
// LDS rows padded to LDK=136 ushorts (272B, 16B-aligned).
// Frag layouts (HW-verified m89): A/B lane holds 8 elems at k=quad*8+j;
// C/D col=lane&15, row=quad*4+reg.
// ---------------------------------------------------------------------------
#define GBN 128
#define LDK 136

__global__ __launch_bounds__(256) void k_gemm_bf(const unsigned short* __restrict__ aggbh,
                                                 const float* __restrict__ Wm,
                                                 const float* __restrict__ bias,
                                                 float* __restrict__ out, int N) {
  __shared__ unsigned short sA[GBN * LDK];
  __shared__ unsigned short sW[GBN * LDK];
  const int tid = threadIdx.x;
  const int n0 = blockIdx.x * GBN;

  // stage A: 128 rows x 256B = 2048 uint4; 8 per thread
#pragma unroll
  for (int i = 0; i < 8; ++i) {
    int q = i * 256 + tid;
    int row = q >> 4;          // 0..127
    int c16 = q & 15;          // 16B chunk in row
    uint4 v = make_uint4(0u, 0u, 0u, 0u);
    if (n0 + row < N)
      v = reinterpret_cast<const uint4*>(aggbh + (size_t)(n0 + row) * D)[c16];
    *reinterpret_cast<uint4*>(&sA[row * LDK + c16 * 8]) = v;
  }
  // stage W with fp32->bf16 cast: 4096 float4; 16 per thread
#pragma unroll
  for (int i = 0; i < 16; ++i) {
    int q = i * 256 + tid;
    int row = q >> 5;
    int c4 = q & 31;
    float4 wv = reinterpret_cast<const float4*>(Wm + (size_t)row * D)[c4];
    ushort4 uw;
    uw.x = (unsigned short)bf16_rne(wv.x);
    uw.y = (unsigned short)bf16_rne(wv.y);
    uw.z = (unsigned short)bf16_rne(wv.z);
    uw.w = (unsigned short)bf16_rne(wv.w);
    *reinterpret_cast<ushort4*>(&sW[row * LDK + c4 * 4]) = uw;
  }
  __syncthreads();

  const int wave = tid >> 6;
  const int lane = tid & 63;
  const int lrow = lane & 15;
  const int quad = lane >> 4;

  floatx4 acc[2][8];
#pragma unroll
  for (int mt = 0; mt < 2; ++mt)
#pragma unroll
    for (int nt = 0; nt < 8; ++nt)
      acc[mt][nt] = (floatx4){0.f, 0.f, 0.f, 0.f};

  float bv[8];
#pragma unroll
  for (int nt = 0; nt < 8; ++nt) bv[nt] = bias[nt * 16 + lrow];

#pragma unroll
  for (int ks = 0; ks < 4; ++ks) {
    int koff = ks * 32 + quad * 8;
    short8 a0 = *reinterpret_cast<const short8*>(&sA[(wave * 32 + lrow) * LDK + koff]);
    short8 a1 = *reinterpret_cast<const short8*>(&sA[(wave * 32 + 16 + lrow) * LDK + koff]);
#pragma unroll
    for (int nt = 0; nt < 8; ++nt) {
      short8 b = *reinterpret_cast<const short8*>(&sW[(nt * 16 + lrow) * LDK + koff]);
      acc[0][nt] = __builtin_amdgcn_mfma_f32_16x16x32_bf16(a0, b, acc[0][nt], 0, 0, 0);
      acc[1][nt] = __builtin_amdgcn_mfma_f32_16x16x32_bf16(a1, b, acc[1][nt], 0, 0, 0);
    }
  }

#pragma unroll
  for (int mt = 0; mt < 2; ++mt) {
    int rbase = n0 + wave * 32 + mt * 16 + quad * 4;
#pragma unroll
    for (int reg = 0; reg < 4; ++reg) {
      int r = rbase + reg;
      if (r < N) {
        float* op = out + (size_t)r * D + lrow;
#pragma unroll
        for (int nt = 0; nt < 8; ++nt)
          op[nt * 16] = acc[mt][nt][reg] + bv[nt];
      }
    }
  }
}

// ---------------------------------------------------------------------------
// fallback fp32 VALU GEMM (R2/R4-proven, in-place safe)
// ---------------------------------------------------------------------------
#define BN 128
#define KC 32
#define LDP 132

__global__ __launch_bounds__(256) void k_gemm(const float* __restrict__ agg,
                                              const float* __restrict__ Wm,
                                              const float* __restrict__ bias,
                                              float* __restrict__ out, int N) {
  __shared__ float sA[KC][LDP];
  __shared__ float sW[KC][LDP];
  const int tid = threadIdx.x;
  const int tx = tid & 15;
  const int ty = tid >> 4;
  const int n0 = blockIdx.x * BN;

  float acc[8][8];
#pragma unroll
  for (int i = 0; i < 8; ++i)
#pragma unroll
    for (int j = 0; j < 8; ++j) acc[i][j] = 0.f;

  const int nl = tid >> 3;
  const int kq = tid & 7;

  for (int kc = 0; kc < D; kc += KC) {
#pragma unroll
    for (int i = 0; i < 4; ++i) {
      int rrow = nl + i * 32;
      int n = n0 + rrow;
      float4 av = make_float4(0.f, 0.f, 0.f, 0.f);
      if (n < N)
        av = reinterpret_cast<const float4*>(agg + (size_t)n * D + kc)[kq];
      int k = kq * 4;
      sA[k+0][rrow] = av.x; sA[k+1][rrow] = av.y;
      sA[k+2][rrow] = av.z; sA[k+3][rrow] = av.w;
      float4 wv = reinterpret_cast<const float4*>(Wm + (size_t)rrow * D + kc)[kq];
      sW[k+0][rrow] = wv.x; sW[k+1][rrow] = wv.y;
      sW[k+2][rrow] = wv.z; sW[k+3][rrow] = wv.w;
    }
    __syncthreads();
#pragma unroll
    for (int k = 0; k < KC; ++k) {
      float4 a0 = *reinterpret_cast<const float4*>(&sA[k][ty * 8]);
      float4 a1 = *reinterpret_cast<const float4*>(&sA[k][ty * 8 + 4]);
      float4 w0 = *reinterpret_cast<const float4*>(&sW[k][tx * 8]);
      float4 w1 = *reinterpret_cast<const float4*>(&sW[k][tx * 8 + 4]);
      float a[8] = {a0.x, a0.y, a0.z, a0.w, a1.x, a1.y, a1.z, a1.w};
      float w[8] = {w0.x, w0.y, w0.z, w0.w, w1.x, w1.y, w1.z, w1.w};
#pragma unroll
      for (int i = 0; i < 8; ++i)
#pragma unroll
        for (int j = 0; j < 8; ++j)
          acc[i][j] += a[i] * w[j];
    }
    __syncthreads();
  }

  float4 b0 = reinterpret_cast<const float4*>(bias)[tx * 2];
  float4 b1 = reinterpret_cast<const float4*>(bias)[tx * 2 + 1];
#pragma unroll
  for (int i = 0; i < 8; ++i) {
    int n = n0 + ty * 8 + i;
    if (n < N) {
      float4 v0 = make_float4(acc[i][0] + b0.x, acc[i][1] + b0.y,
                              acc[i][2] + b0.z, acc[i][3] + b0.w);
      float4 v1 = make_float4(acc[i][4] + b1.x, acc[i][5] + b1.y,
                              acc[i][6] + b1.z, acc[i][7] + b1.w);
      float4* op = reinterpret_cast<float4*>(out + (size_t)n * D + tx * 8);
      op[0] = v0;
      op[1] = v1;
    }
  }
}

// ---------------------------------------------------------------------------
extern "C" void kernel_launch(void* const* d_in, const int* in_sizes, int n_in,
                              void* d_out, int out_size, void* d_ws, size_t ws_size,
                              hipStream_t stream) {
  const float* x    = (const float*)d_in[0];
  const int*   ei   = (const int*)d_in[1];
  const float* Wm   = (const float*)d_in[2];
  const float* bias = (const float*)d_in[3];
  float* out = (float*)d_out;

  const int N = in_sizes[0] / D;
  const int E = in_sizes[1] / 2;
  const int NB = (N + NPB - 1) >> SHIFT;

  // ws layout: counts|bases|cursor | slots[N*10] | xh (N*256B) | aggbh (N*256B)
  int* counts = (int*)d_ws;
  int* bases  = counts + NB;
  int* cursor = bases + NB;
  size_t off_slots = ((size_t)(3 * NB) * 4 + 15) & ~(size_t)15;
  int* slots = (int*)((char*)d_ws + off_slots);
  size_t off_xh = (off_slots + (size_t)N * KNB * 4 + 15) & ~(size_t)15;
  unsigned* xh = (unsigned*)((char*)d_ws + off_xh);
  size_t off_ab = off_xh + (size_t)N * D * 2;
  unsigned* aggbh = (unsigned*)((char*)d_ws + off_ab);

  const bool have_xh = ws_size >= off_xh + (size_t)N * D * 2;
  const bool have_ab = ws_size >= off_ab + (size_t)N * D * 2;

  unsigned* binned = (unsigned*)d_out;  // staged in d_out, dead after k_select
  const int blocks_bin = (E + EPB - 1) / EPB;
  const int S = N * KNB;
  const int n8 = N * (D / 8);
  const int xblocks = have_xh ? (n8 + T_BIN - 1) / T_BIN : 0;

  k_init2<<<(S + 255) / 256, 256, 0, stream>>>(counts, NB, slots, S);
  k_count_xcast<<<blocks_bin + xblocks, T_BIN, 0, stream>>>(ei, E, NB, counts,
                                                            blocks_bin, x, xh, n8);
  k_scan<<<1, MAXNB, 0, stream>>>(counts, NB, bases, cursor);
  k_scatter2<<<blocks_bin, T_BIN, 0, stream>>>(ei, E, NB, cursor, binned);
  k_select<<<NB, 256, 0, stream>>>(binned, bases, counts, slots, N, E);

  if (have_ab) {
    // fast: bf16 agg in ws + MFMA gemm (no aliasing)
    k_agg_hb<<<(N + 3) / 4, 256, 0, stream>>>(xh, x, ei, slots, aggbh, N, E);
    k_gemm_bf<<<(N + GBN - 1) / GBN, 256, 0, stream>>>(
        (const unsigned short*)aggbh, Wm, bias, out, N);
  } else if (have_xh) {
    // mid: bf16 gather, fp32 agg in d_out, fp32 gemm in place (R4 path)
    k_agg_h<<<(N + 3) / 4, 256, 0, stream>>>(xh, x, ei, slots, out, N, E);
    k_gemm<<<(N + BN - 1) / BN, 256, 0, stream>>>(out, Wm, bias, out, N);
  } else {
    // slow: fp32 gather, fp32 gemm (R2 path)
    k_agg<<<(N + 3) / 4, 256, 0, stream>>>(x, ei, slots, out, N, E);
    k_gemm<<<(N + BN - 1) / BN, 256, 0, stream>>>(out, Wm, bias, out, N);
  }
}

// Round 6
// 240.775 us; speedup vs baseline: 2.9722x; 1.0370x over previous
//
#include <hip/hip_runtime.h>
#include <hip/hip_bf16.h>
#include <cstdint>
#include <cstddef>

#define D 128           // feature dim
#define KNB 10          // NUM_NEIGHBORS
#define SENT 0x7FFFFFFF
#define SHIFT 8         // nodes per bucket = 256
#define NPB 256
#define T_BIN 256
#define EPB 4096        // edges per binning block
#define MAXNB 1024

typedef __attribute__((ext_vector_type(8))) short short8;   // MFMA A/B frag (8 bf16)
typedef __attribute__((ext_vector_type(4))) float floatx4;  // MFMA C/D frag

__device__ inline unsigned bf16_rne(float f) {
  unsigned u = __builtin_bit_cast(unsigned, f);
  return (u + 0x7FFFu + ((u >> 16) & 1u)) >> 16;
}

// ---------------------------------------------------------------------------
// k_init2: counts[0..NB)=0 and slots[0..S)=SENT in one launch (grid covers S)
// ---------------------------------------------------------------------------
__global__ __launch_bounds__(256) void k_init2(int* __restrict__ counts, int NB,
                                               int* __restrict__ slots, int S) {
  int i = blockIdx.x * 256 + threadIdx.x;
  if (i < NB) counts[i] = 0;
  if (i < S) slots[i] = SENT;
}

// ---------------------------------------------------------------------------
// k_count_xcast: blocks [0,blocks_bin) do the LDS-histogram edge count;
// blocks [blocks_bin,..) stream-cast x fp32 -> xh bf16 pairs (overlapped).
// ---------------------------------------------------------------------------
__global__ __launch_bounds__(T_BIN) void k_count_xcast(const int* __restrict__ row, int E,
                                                       int NB, int* __restrict__ counts,
                                                       int blocks_bin,
                                                       const float* __restrict__ x,
                                                       unsigned* __restrict__ xh, int n8) {
  if ((int)blockIdx.x < blocks_bin) {
    __shared__ int hist[MAXNB];
    for (int i = threadIdx.x; i < NB; i += T_BIN) hist[i] = 0;
    __syncthreads();
    int e0 = blockIdx.x * EPB;
    for (int i = threadIdx.x; i < EPB; i += T_BIN) {
      int e = e0 + i;
      if (e < E) atomicAdd(&hist[row[e] >> SHIFT], 1);
    }
    __syncthreads();
    for (int i = threadIdx.x; i < NB; i += T_BIN)
      if (hist[i]) atomicAdd(&counts[i], hist[i]);
  } else {
    int t = ((int)blockIdx.x - blocks_bin) * T_BIN + threadIdx.x;
    if (t >= n8) return;
    const float4* p = reinterpret_cast<const float4*>(x) + (size_t)t * 2;
    float4 a = p[0], b = p[1];
    uint4 o;
    o.x = bf16_rne(a.x) | (bf16_rne(a.y) << 16);
    o.y = bf16_rne(a.z) | (bf16_rne(a.w) << 16);
    o.z = bf16_rne(b.x) | (bf16_rne(b.y) << 16);
    o.w = bf16_rne(b.z) | (bf16_rne(b.w) << 16);
    reinterpret_cast<uint4*>(xh)[t] = o;
  }
}

// ---------------------------------------------------------------------------
__global__ __launch_bounds__(MAXNB) void k_scan(const int* __restrict__ counts, int NB,
                                                int* __restrict__ bases,
                                                int* __restrict__ cursor) {
  __shared__ int buf[MAXNB];
  int t = threadIdx.x;
  int v = (t < NB) ? counts[t] : 0;
  buf[t] = v;
  __syncthreads();
  for (int off = 1; off < MAXNB; off <<= 1) {
    int xv = (t >= off) ? buf[t - off] : 0;
    __syncthreads();
    buf[t] += xv;
    __syncthreads();
  }
  if (t < NB) {
    int base = buf[t] - v;
    bases[t] = base;
    cursor[t] = base;
  }
}

// ---------------------------------------------------------------------------
// bin edges into bucket regions; entry = (row&255)<<24 | edge_id (E < 2^24)
// ---------------------------------------------------------------------------
__global__ __launch_bounds__(T_BIN) void k_scatter2(const int* __restrict__ row, int E,
                                                    int NB, int* __restrict__ cursor,
                                                    unsigned* __restrict__ binned) {
  __shared__ int hist[MAXNB];
  __shared__ int lbase[MAXNB];
  for (int i = threadIdx.x; i < NB; i += T_BIN) hist[i] = 0;
  __syncthreads();
  int e0 = blockIdx.x * EPB;
  for (int i = threadIdx.x; i < EPB; i += T_BIN) {
    int e = e0 + i;
    if (e < E) atomicAdd(&hist[row[e] >> SHIFT], 1);
  }
  __syncthreads();
  for (int i = threadIdx.x; i < NB; i += T_BIN) {
    int h = hist[i];
    lbase[i] = h ? atomicAdd(&cursor[i], h) : 0;
  }
  __syncthreads();
  for (int i = threadIdx.x; i < NB; i += T_BIN) hist[i] = 0;  // reuse as cursor
  __syncthreads();
  for (int i = threadIdx.x; i < EPB; i += T_BIN) {
    int e = e0 + i;
    if (e < E) {
      int r = row[e];
      int b = r >> SHIFT;
      int pos = lbase[b] + atomicAdd(&hist[b], 1);
      binned[pos] = ((unsigned)(r & (NPB - 1)) << 24) | (unsigned)e;
    }
  }
}

// ---------------------------------------------------------------------------
// one WG per bucket: LDS atomicMin cascade -> 10 smallest edge ids per node
// ---------------------------------------------------------------------------
__global__ __launch_bounds__(256) void k_select(const unsigned* __restrict__ binned,
                                                const int* __restrict__ bases,
                                                const int* __restrict__ counts,
                                                int* __restrict__ slots_g, int N, int E) {
  __shared__ int sl[NPB * KNB];
  int b = blockIdx.x;
  int nbase = b << SHIFT;
  int nloc = min(NPB, N - nbase);
  for (int i = threadIdx.x; i < nloc * KNB; i += 256) sl[i] = SENT;
  __syncthreads();
  int base = bases[b];
  int cnt = counts[b];
  if (cnt > E) cnt = E;  // hardening
  for (int i = threadIdx.x; i < cnt; i += 256) {
    unsigned en = binned[base + i];
    int rl = (int)(en >> 24);
    int v = (int)(en & 0xFFFFFFu);
    int* s = &sl[rl * KNB];
#pragma unroll
    for (int k = 0; k < KNB; ++k) {
      int old = atomicMin(&s[k], v);
      if (old == SENT) break;
      v = v > old ? v : old;
    }
  }
  __syncthreads();
  for (int i = threadIdx.x; i < nloc * KNB; i += 256)
    slots_g[(size_t)nbase * KNB + i] = sl[i];
}

// ---------------------------------------------------------------------------
// k_agg_hb: neighbor mean via bf16 gather, fp32 accumulate, bf16 packed out.
// R6: fixed-trip fully-unrolled 10-load pipeline — all cols broadcast first,
// then 10 INDEPENDENT gathers into registers (invalid -> row 0, weight 0),
// then accumulate. 10 outstanding loads/wave vs ~1 in the old while(mask)
// loop (which was latency-serialized: shfl+load+add chain per neighbor).
// HARDENING (load-bearing, see R3/R5 post-mortems): (unsigned)eid < E rejects
// SENT and poison-derived values; col range-checked before indexing xh.
// ---------------------------------------------------------------------------
__global__ __launch_bounds__(256) void k_agg_hb(const unsigned* __restrict__ xh,
                                                const float* __restrict__ x,
                                                const int* __restrict__ ei,
                                                const int* __restrict__ slots,
                                                unsigned* __restrict__ aggbh,
                                                int N, int E) {
  int wave = threadIdx.x >> 6;
  int lane = threadIdx.x & 63;
  int n = blockIdx.x * 4 + wave;
  if (n >= N) return;

  int eid = SENT;
  if (lane < KNB) eid = slots[(size_t)n * KNB + lane];
  bool valid = (lane < KNB) && ((unsigned)eid < (unsigned)E);
  int nsel = __popcll(__ballot(valid));
  int c = valid ? ei[(size_t)E + eid] : -1;   // -1 = invalid marker

  unsigned uu[KNB];
  float wj[KNB];
#pragma unroll
  for (int j = 0; j < KNB; ++j) {
    int cj = __shfl(c, j);                    // slot j's col, wave-uniform
    bool vj = (unsigned)cj < (unsigned)N;     // real cols are in [0,N); -1 fails
    wj[j] = vj ? 1.f : 0.f;
    uu[j] = xh[(size_t)(vj ? cj : 0) * 64 + lane];  // row 0 = hot line when invalid
  }

  float ax = 0.f, ay = 0.f;
  if (nsel > 0) {
#pragma unroll
    for (int j = 0; j < KNB; ++j) {
      ax += wj[j] * __builtin_bit_cast(float, uu[j] << 16);
      ay += wj[j] * __builtin_bit_cast(float, uu[j] & 0xFFFF0000u);
    }
    float sc = 1.f / (float)nsel;
    ax *= sc; ay *= sc;
  } else {
    float2 v = reinterpret_cast<const float2*>(x + (size_t)n * D)[lane];
    ax = v.x; ay = v.y;
  }
  aggbh[(size_t)n * 64 + lane] = bf16_rne(ax) | (bf16_rne(ay) << 16);
}

// ---------------------------------------------------------------------------
// fallback fp32-agg variants (R4-proven), used when ws is small
// ---------------------------------------------------------------------------
__global__ __launch_bounds__(256) void k_agg_h(const unsigned* __restrict__ xh,
                                               const float* __restrict__ x,
                                               const int* __restrict__ ei,
                                               const int* __restrict__ slots,
                                               float* __restrict__ agg, int N, int E) {
  int wave = threadIdx.x >> 6;
  int lane = threadIdx.x & 63;
  int n = blockIdx.x * 4 + wave;
  if (n >= N) return;
  int eid = SENT;
  if (lane < KNB) eid = slots[(size_t)n * KNB + lane];
  bool valid = (lane < KNB) && ((unsigned)eid < (unsigned)E);
  unsigned long long m = __ballot(valid);
  int nsel = __popcll(m);
  int c = valid ? ei[(size_t)E + eid] : 0;
  float ax = 0.f, ay = 0.f;
  if (nsel > 0) {
    unsigned long long mm = m;
    while (mm) {
      int j = (int)__builtin_ctzll(mm);
      mm &= mm - 1;
      int cj = __shfl(c, j);
      if ((unsigned)cj >= (unsigned)N) cj = 0;
      unsigned u = xh[(size_t)cj * 64 + lane];
      ax += __builtin_bit_cast(float, u << 16);
      ay += __builtin_bit_cast(float, u & 0xFFFF0000u);
    }
    float sc = 1.f / (float)nsel;
    ax *= sc; ay *= sc;
  } else {
    float2 v = reinterpret_cast<const float2*>(x + (size_t)n * D)[lane];
    ax = v.x; ay = v.y;
  }
  reinterpret_cast<float2*>(agg + (size_t)n * D)[lane] = make_float2(ax, ay);
}

__global__ __launch_bounds__(256) void k_agg(const float* __restrict__ x,
                                             const int* __restrict__ ei,
                                             const int* __restrict__ slots,
                                             float* __restrict__ agg,
                                             int N, int E) {
  int wave = threadIdx.x >> 6;
  int lane = threadIdx.x & 63;
  int n = blockIdx.x * 4 + wave;
  if (n >= N) return;
  int eid = SENT;
  if (lane < KNB) eid = slots[(size_t)n * KNB + lane];
  bool valid = (lane < KNB) && ((unsigned)eid < (unsigned)E);
  unsigned long long m = __ballot(valid);
  int nsel = __popcll(m);
  int c = valid ? ei[(size_t)E + eid] : 0;
  float2 acc = make_float2(0.f, 0.f);
  if (nsel > 0) {
    unsigned long long mm = m;
    while (mm) {
      int j = (int)__builtin_ctzll(mm);
      mm &= mm - 1;
      int cj = __shfl(c, j);
      if ((unsigned)cj >= (unsigned)N) cj = 0;
      float2 v = reinterpret_cast<const float2*>(x + (size_t)cj * D)[lane];
      acc.x += v.x; acc.y += v.y;
    }
    float sc = 1.f / (float)nsel;
    acc.x *= sc; acc.y *= sc;
  } else {
    acc = reinterpret_cast<const float2*>(x + (size_t)n * D)[lane];
  }
  reinterpret_cast<float2*>(agg + (size_t)n * D)[lane] = acc;
}

// ---------------------------------------------------------------------------
// k_gemm_bf: out[n][o] = b[o] + sum_k aggbh[n][k]*W[o][k], bf16 MFMA 16x16x32.
// A read from ws (bf16), out only written -> no aliasing at all.
// Frag layouts (HW-verified m89): A/B lane holds 8 elems at k=quad*8+j;
// C/D col=lane&15, row=quad*4+reg.
// ---------------------------------------------------------------------------
#define GBN 128
#define LDK 136

__global__ __launch_bounds__(256) void k_gemm_bf(const unsigned short* __restrict__ aggbh,
                                                 const float* __restrict__ Wm,
                                                 const float* __restrict__ bias,
                                                 float* __restrict__ out, int N) {
  __shared__ unsigned short sA[GBN * LDK];
  __shared__ unsigned short sW[GBN * LDK];
  const int tid = threadIdx.x;
  const int n0 = blockIdx.x * GBN;

#pragma unroll
  for (int i = 0; i < 8; ++i) {
    int q = i * 256 + tid;
    int row = q >> 4;
    int c16 = q & 15;
    uint4 v = make_uint4(0u, 0u, 0u, 0u);
    if (n0 + row < N)
      v = reinterpret_cast<const uint4*>(aggbh + (size_t)(n0 + row) * D)[c16];
    *reinterpret_cast<uint4*>(&sA[row * LDK + c16 * 8]) = v;
  }
#pragma unroll
  for (int i = 0; i < 16; ++i) {
    int q = i * 256 + tid;
    int row = q >> 5;
    int c4 = q & 31;
    float4 wv = reinterpret_cast<const float4*>(Wm + (size_t)row * D)[c4];
    ushort4 uw;
    uw.x = (unsigned short)bf16_rne(wv.x);
    uw.y = (unsigned short)bf16_rne(wv.y);
    uw.z = (unsigned short)bf16_rne(wv.z);
    uw.w = (unsigned short)bf16_rne(wv.w);
    *reinterpret_cast<ushort4*>(&sW[row * LDK + c4 * 4]) = uw;
  }
  __syncthreads();

  const int wave = tid >> 6;
  const int lane = tid & 63;
  const int lrow = lane & 15;
  const int quad = lane >> 4;

  floatx4 acc[2][8];
#pragma unroll
  for (int mt = 0; mt < 2; ++mt)
#pragma unroll
    for (int nt = 0; nt < 8; ++nt)
      acc[mt][nt] = (floatx4){0.f, 0.f, 0.f, 0.f};

  float bv[8];
#pragma unroll
  for (int nt = 0; nt < 8; ++nt) bv[nt] = bias[nt * 16 + lrow];

#pragma unroll
  for (int ks = 0; ks < 4; ++ks) {
    int koff = ks * 32 + quad * 8;
    short8 a0 = *reinterpret_cast<const short8*>(&sA[(wave * 32 + lrow) * LDK + koff]);
    short8 a1 = *reinterpret_cast<const short8*>(&sA[(wave * 32 + 16 + lrow) * LDK + koff]);
#pragma unroll
    for (int nt = 0; nt < 8; ++nt) {
      short8 b = *reinterpret_cast<const short8*>(&sW[(nt * 16 + lrow) * LDK + koff]);
      acc[0][nt] = __builtin_amdgcn_mfma_f32_16x16x32_bf16(a0, b, acc[0][nt], 0, 0, 0);
      acc[1][nt] = __builtin_amdgcn_mfma_f32_16x16x32_bf16(a1, b, acc[1][nt], 0, 0, 0);
    }
  }

#pragma unroll
  for (int mt = 0; mt < 2; ++mt) {
    int rbase = n0 + wave * 32 + mt * 16 + quad * 4;
#pragma unroll
    for (int reg = 0; reg < 4; ++reg) {
      int r = rbase + reg;
      if (r < N) {
        float* op = out + (size_t)r * D + lrow;
#pragma unroll
        for (int nt = 0; nt < 8; ++nt)
          op[nt * 16] = acc[mt][nt][reg] + bv[nt];
      }
    }
  }
}

// ---------------------------------------------------------------------------
// fallback fp32 VALU GEMM (R2/R4-proven, in-place safe)
// ---------------------------------------------------------------------------
#define BN 128
#define KC 32
#define LDP 132

__global__ __launch_bounds__(256) void k_gemm(const float* __restrict__ agg,
                                              const float* __restrict__ Wm,
                                              const float* __restrict__ bias,
                                              float* __restrict__ out, int N) {
  __shared__ float sA[KC][LDP];
  __shared__ float sW[KC][LDP];
  const int tid = threadIdx.x;
  const int tx = tid & 15;
  const int ty = tid >> 4;
  const int n0 = blockIdx.x * BN;

  float acc[8][8];
#pragma unroll
  for (int i = 0; i < 8; ++i)
#pragma unroll
    for (int j = 0; j < 8; ++j) acc[i][j] = 0.f;

  const int nl = tid >> 3;
  const int kq = tid & 7;

  for (int kc = 0; kc < D; kc += KC) {
#pragma unroll
    for (int i = 0; i < 4; ++i) {
      int rrow = nl + i * 32;
      int n = n0 + rrow;
      float4 av = make_float4(0.f, 0.f, 0.f, 0.f);
      if (n < N)
        av = reinterpret_cast<const float4*>(agg + (size_t)n * D + kc)[kq];
      int k = kq * 4;
      sA[k+0][rrow] = av.x; sA[k+1][rrow] = av.y;
      sA[k+2][rrow] = av.z; sA[k+3][rrow] = av.w;
      float4 wv = reinterpret_cast<const float4*>(Wm + (size_t)rrow * D + kc)[kq];
      sW[k+0][rrow] = wv.x; sW[k+1][rrow] = wv.y;
      sW[k+2][rrow] = wv.z; sW[k+3][rrow] = wv.w;
    }
    __syncthreads();
#pragma unroll
    for (int k = 0; k < KC; ++k) {
      float4 a0 = *reinterpret_cast<const float4*>(&sA[k][ty * 8]);
      float4 a1 = *reinterpret_cast<const float4*>(&sA[k][ty * 8 + 4]);
      float4 w0 = *reinterpret_cast<const float4*>(&sW[k][tx * 8]);
      float4 w1 = *reinterpret_cast<const float4*>(&sW[k][tx * 8 + 4]);
      float a[8] = {a0.x, a0.y, a0.z, a0.w, a1.x, a1.y, a1.z, a1.w};
      float w[8] = {w0.x, w0.y, w0.z, w0.w, w1.x, w1.y, w1.z, w1.w};
#pragma unroll
      for (int i = 0; i < 8; ++i)
#pragma unroll
        for (int j = 0; j < 8; ++j)
          acc[i][j] += a[i] * w[j];
    }
    __syncthreads();
  }

  float4 b0 = reinterpret_cast<const float4*>(bias)[tx * 2];
  float4 b1 = reinterpret_cast<const float4*>(bias)[tx * 2 + 1];
#pragma unroll
  for (int i = 0; i < 8; ++i) {
    int n = n0 + ty * 8 + i;
    if (n < N) {
      float4 v0 = make_float4(acc[i][0] + b0.x, acc[i][1] + b0.y,
                              acc[i][2] + b0.z, acc[i][3] + b0.w);
      float4 v1 = make_float4(acc[i][4] + b1.x, acc[i][5] + b1.y,
                              acc[i][6] + b1.z, acc[i][7] + b1.w);
      float4* op = reinterpret_cast<float4*>(out + (size_t)n * D + tx * 8);
      op[0] = v0;
      op[1] = v1;
    }
  }
}

// ---------------------------------------------------------------------------
extern "C" void kernel_launch(void* const* d_in, const int* in_sizes, int n_in,
                              void* d_out, int out_size, void* d_ws, size_t ws_size,
                              hipStream_t stream) {
  const float* x    = (const float*)d_in[0];
  const int*   ei   = (const int*)d_in[1];
  const float* Wm   = (const float*)d_in[2];
  const float* bias = (const float*)d_in[3];
  float* out = (float*)d_out;

  const int N = in_sizes[0] / D;
  const int E = in_sizes[1] / 2;
  const int NB = (N + NPB - 1) >> SHIFT;

  // ws layout: counts|bases|cursor | slots[N*10] | xh (N*256B) | aggbh (N*256B)
  int* counts = (int*)d_ws;
  int* bases  = counts + NB;
  int* cursor = bases + NB;
  size_t off_slots = ((size_t)(3 * NB) * 4 + 15) & ~(size_t)15;
  int* slots = (int*)((char*)d_ws + off_slots);
  size_t off_xh = (off_slots + (size_t)N * KNB * 4 + 15) & ~(size_t)15;
  unsigned* xh = (unsigned*)((char*)d_ws + off_xh);
  size_t off_ab = off_xh + (size_t)N * D * 2;
  unsigned* aggbh = (unsigned*)((char*)d_ws + off_ab);

  const bool have_xh = ws_size >= off_xh + (size_t)N * D * 2;
  const bool have_ab = ws_size >= off_ab + (size_t)N * D * 2;

  unsigned* binned = (unsigned*)d_out;  // staged in d_out, dead after k_select
  const int blocks_bin = (E + EPB - 1) / EPB;
  const int S = N * KNB;
  const int n8 = N * (D / 8);
  const int xblocks = have_xh ? (n8 + T_BIN - 1) / T_BIN : 0;

  k_init2<<<(S + 255) / 256, 256, 0, stream>>>(counts, NB, slots, S);
  k_count_xcast<<<blocks_bin + xblocks, T_BIN, 0, stream>>>(ei, E, NB, counts,
                                                            blocks_bin, x, xh, n8);
  k_scan<<<1, MAXNB, 0, stream>>>(counts, NB, bases, cursor);
  k_scatter2<<<blocks_bin, T_BIN, 0, stream>>>(ei, E, NB, cursor, binned);
  k_select<<<NB, 256, 0, stream>>>(binned, bases, counts, slots, N, E);

  if (have_ab) {
    k_agg_hb<<<(N + 3) / 4, 256, 0, stream>>>(xh, x, ei, slots, aggbh, N, E);
    k_gemm_bf<<<(N + GBN - 1) / GBN, 256, 0, stream>>>(
        (const unsigned short*)aggbh, Wm, bias, out, N);
  } else if (have_xh) {
    k_agg_h<<<(N + 3) / 4, 256, 0, stream>>>(xh, x, ei, slots, out, N, E);
    k_gemm<<<(N + BN - 1) / BN, 256, 0, stream>>>(out, Wm, bias, out, N);
  } else {
    k_agg<<<(N + 3) / 4, 256, 0, stream>>>(x, ei, slots, out, N, E);
    k_gemm<<<(N + BN - 1) / BN, 256, 0, stream>>>(out, Wm, bias, out, N);
  }
}